// Round 2
// baseline (605.729 us; speedup 1.0000x reference)
//
#include <hip/hip_runtime.h>

// PPAModel: node encoder (2-layer MLP) -> edge gather/concat -> edge MLP -> sigmoid
// IN=128, HID=256, OUT=128, N_NODES=100000, N_EDGES=1000000
//
// ws layout:
//   [0,256)            : int flag (1 => edge_index stored as int64)
//   [256, +64KB)       : W1 bf16 swizzled  [k/8][n][k%8], K=128,N=256
//   [65792, +64KB)     : W2 bf16 swizzled  K=256,N=128
//   [131328, +128KB)   : W3 bf16 swizzled  K=256,N=256
//   [262400, +25.6MB)  : h table bf16 [100000][128]

#define NN 100000
#define NE 1000000
#define NT 15625     // NE/64 edge tiles
#define TPB 5        // tiles per block (3125 * 5 == 15625, exact)

typedef __attribute__((ext_vector_type(8))) __bf16 bf16x8;
typedef __attribute__((ext_vector_type(4))) float f32x4;
typedef __attribute__((ext_vector_type(4))) unsigned short us4;

__device__ __forceinline__ unsigned short f2bf(float f) {
    unsigned u = __float_as_uint(f);
    return (unsigned short)((u + 0x7FFFu + ((u >> 16) & 1u)) >> 16);
}

// ---------------- prep: swizzle weights to bf16, detect index dtype -------
__global__ void prep_kernel(const float* __restrict__ W1,
                            const float* __restrict__ W2,
                            const float* __restrict__ W3,
                            const void* __restrict__ eidx,
                            unsigned short* __restrict__ w1s,
                            unsigned short* __restrict__ w2s,
                            unsigned short* __restrict__ w3s,
                            int* __restrict__ flag) {
    int t = blockIdx.x * blockDim.x + threadIdx.x;
    if (t < 32768) {                       // W1: K=128, N=256
        int k = t >> 8, n = t & 255;
        w1s[(k >> 3) * 2048 + n * 8 + (k & 7)] = f2bf(W1[t]);
    } else if (t < 65536) {                // W2: K=256, N=128
        int i = t - 32768;
        int k = i >> 7, n = i & 127;
        w2s[(k >> 3) * 1024 + n * 8 + (k & 7)] = f2bf(W2[i]);
    } else if (t < 131072) {               // W3: K=256, N=256
        int i = t - 65536;
        int k = i >> 8, n = i & 255;
        w3s[(k >> 3) * 2048 + n * 8 + (k & 7)] = f2bf(W3[i]);
    }
    if (t == 0) {
        const unsigned* u = (const unsigned*)eidx;
        int all0 = 1;
        for (int i = 0; i < 32; ++i) all0 &= (u[2 * i + 1] == 0u);
        *flag = all0;
    }
}

// ---------------- phase 1: fused node encoder -----------------------------
// per block: 64 nodes. B-fragments read straight from L2-resident swizzled
// weights (no LDS weight staging). LDS only holds A-tiles.
__global__ __launch_bounds__(256, 2) void node_enc(
    const float* __restrict__ x, const float* __restrict__ b1,
    const float* __restrict__ b2, const unsigned short* __restrict__ w1s,
    const unsigned short* __restrict__ w2s, unsigned short* __restrict__ hbf) {
    __shared__ __align__(16) unsigned short A1[64 * 136];  // 17408 B
    __shared__ __align__(16) unsigned short A2[64 * 264];  // 33792 B

    const int t = threadIdx.x, lane = t & 63, w = t >> 6;
    const int cl = lane & 15, q = lane >> 4;
    const int m0 = blockIdx.x * 64;

    // stage A1: x rows f32 -> bf16
    {
        const float4* x4 = (const float4*)x;
#pragma unroll
        for (int i = 0; i < 8; ++i) {
            int lin = i * 256 + t;
            int m = lin >> 5, c = lin & 31;
            int node = m0 + m;
            if (node > NN - 1) node = NN - 1;
            float4 v = x4[node * 32 + c];
            us4 b;
            b.x = f2bf(v.x); b.y = f2bf(v.y); b.z = f2bf(v.z); b.w = f2bf(v.w);
            *(us4*)(A1 + m * 136 + c * 4) = b;
        }
    }
    __syncthreads();

    // GEMM1: [64x128]x[128x256], each wave owns 64 N-cols, bias in acc init
    const int nb = w * 64;
    float b1v[4];
#pragma unroll
    for (int nt = 0; nt < 4; ++nt) b1v[nt] = b1[nb + nt * 16 + cl];
    f32x4 acc[4][4];
#pragma unroll
    for (int mt = 0; mt < 4; ++mt)
#pragma unroll
        for (int nt = 0; nt < 4; ++nt)
            acc[mt][nt] = (f32x4){b1v[nt], b1v[nt], b1v[nt], b1v[nt]};
#pragma unroll
    for (int s = 0; s < 4; ++s) {   // K=128
        bf16x8 a[4], b[4];
#pragma unroll
        for (int mt = 0; mt < 4; ++mt)
            a[mt] = *(const bf16x8*)(A1 + (mt * 16 + cl) * 136 + s * 32 + q * 8);
#pragma unroll
        for (int nt = 0; nt < 4; ++nt)
            b[nt] = *(const bf16x8*)(w1s + (s * 4 + q) * 2048 + (nb + nt * 16 + cl) * 8);
#pragma unroll
        for (int mt = 0; mt < 4; ++mt)
#pragma unroll
            for (int nt = 0; nt < 4; ++nt)
                acc[mt][nt] = __builtin_amdgcn_mfma_f32_16x16x32_bf16(a[mt], b[nt], acc[mt][nt], 0, 0, 0);
    }

    // relu -> A2 [m][k] bf16 (separate LDS region; one barrier)
#pragma unroll
    for (int mt = 0; mt < 4; ++mt)
#pragma unroll
        for (int nt = 0; nt < 4; ++nt)
#pragma unroll
            for (int r = 0; r < 4; ++r) {
                float v = fmaxf(acc[mt][nt][r], 0.0f);
                A2[(mt * 16 + q * 4 + r) * 264 + nb + nt * 16 + cl] = f2bf(v);
            }
    __syncthreads();

    // GEMM2: [64x256]x[256x128]; each wave owns 32 N-cols, bias in acc init
    const int nb2 = w * 32;
    float b2v[2];
#pragma unroll
    for (int nt = 0; nt < 2; ++nt) b2v[nt] = b2[nb2 + nt * 16 + cl];
    f32x4 acc2[4][2];
#pragma unroll
    for (int mt = 0; mt < 4; ++mt)
#pragma unroll
        for (int nt = 0; nt < 2; ++nt)
            acc2[mt][nt] = (f32x4){b2v[nt], b2v[nt], b2v[nt], b2v[nt]};
#pragma unroll
    for (int s = 0; s < 8; ++s) {   // K=256
        bf16x8 a[4], b[2];
#pragma unroll
        for (int mt = 0; mt < 4; ++mt)
            a[mt] = *(const bf16x8*)(A2 + (mt * 16 + cl) * 264 + s * 32 + q * 8);
#pragma unroll
        for (int nt = 0; nt < 2; ++nt)
            b[nt] = *(const bf16x8*)(w2s + (s * 4 + q) * 1024 + (nb2 + nt * 16 + cl) * 8);
#pragma unroll
        for (int mt = 0; mt < 4; ++mt)
#pragma unroll
            for (int nt = 0; nt < 2; ++nt)
                acc2[mt][nt] = __builtin_amdgcn_mfma_f32_16x16x32_bf16(a[mt], b[nt], acc2[mt][nt], 0, 0, 0);
    }
    // -> h table (bf16)
#pragma unroll
    for (int mt = 0; mt < 4; ++mt)
#pragma unroll
        for (int nt = 0; nt < 2; ++nt)
#pragma unroll
            for (int r = 0; r < 4; ++r) {
                int node = m0 + mt * 16 + q * 4 + r;
                if (node < NN)
                    hbf[node * 128 + nb2 + nt * 16 + cl] = f2bf(acc2[mt][nt][r]);
            }
}

// ---------------- phase 2: edge MLP, 5 tiles/block, double-buffered A -----
__global__ __launch_bounds__(256, 2) void edge_mlp(
    const void* __restrict__ eidx, const unsigned short* __restrict__ hbf,
    const unsigned short* __restrict__ w3s, const float* __restrict__ b3,
    const float* __restrict__ W4, const float* __restrict__ b4,
    const int* __restrict__ flag, float* __restrict__ out) {
    __shared__ __align__(16) unsigned short A[2][64 * 264];  // 2 x 33792 B
    __shared__ float partial[2][4][64];                      // 2 KB

    const int t = threadIdx.x, lane = t & 63, w = t >> 6;
    const int cl = lane & 15, q = lane >> 4;
    const int base = blockIdx.x * TPB;
    const bool i64 = (*flag != 0);
    const int* ei32 = (const int*)eidx;
    const long long* ei64 = (const long long*)eidx;

    // per-wave epilogue constants
    const int nb = w * 64;
    float b3v[4], w4v[4];
#pragma unroll
    for (int nt = 0; nt < 4; ++nt) {
        int n = nb + nt * 16 + cl;
        b3v[nt] = b3[n];
        w4v[nt] = W4[n];
    }
    const float b4v = b4[0];

    // per-thread gather geometry: fixed chunk c, rows mb+8i
    const int c = t & 31;
    const int half = (c < 16) ? 0 : 1;
    const int koff = (c & 15) * 8;   // shorts within a 128-elem h row
    const int mb = t >> 5;           // 0..7

    uint4 g[8];
#define ISSUE_GATHER(tile)                                                   \
    {                                                                        \
        int e0 = (tile) * 64;                                                \
        _Pragma("unroll") for (int i = 0; i < 8; ++i) {                      \
            int e = e0 + i * 8 + mb;                                         \
            int eoff = half ? (NE + e) : e;                                  \
            int node = i64 ? (int)ei64[eoff] : ei32[eoff];                   \
            if (node < 0) node = 0;                                          \
            if (node > NN - 1) node = NN - 1;                                \
            g[i] = *(const uint4*)(hbf + node * 128 + koff);                 \
        }                                                                    \
    }
#define WRITE_A(buf)                                                         \
    {                                                                        \
        _Pragma("unroll") for (int i = 0; i < 8; ++i) {                      \
            int m = i * 8 + mb;                                              \
            *(uint4*)(A[buf] + m * 264 + half * 128 + koff) = g[i];          \
        }                                                                    \
    }

    ISSUE_GATHER(base + 0);
    WRITE_A(0);
    ISSUE_GATHER(base + 1);
    __syncthreads();

    for (int tt = 0; tt < TPB; ++tt) {
        const int buf = tt & 1;
        // MFMA: [64x256]x[256x256], bias b3 folded into acc init
        f32x4 acc[4][4];
#pragma unroll
        for (int mt = 0; mt < 4; ++mt)
#pragma unroll
            for (int nt = 0; nt < 4; ++nt)
                acc[mt][nt] = (f32x4){b3v[nt], b3v[nt], b3v[nt], b3v[nt]};
#pragma unroll
        for (int s = 0; s < 8; ++s) {
            bf16x8 a[4], b[4];
#pragma unroll
            for (int mt = 0; mt < 4; ++mt)
                a[mt] = *(const bf16x8*)(A[buf] + (mt * 16 + cl) * 264 + s * 32 + q * 8);
#pragma unroll
            for (int nt = 0; nt < 4; ++nt)
                b[nt] = *(const bf16x8*)(w3s + (s * 4 + q) * 2048 + (nb + nt * 16 + cl) * 8);
#pragma unroll
            for (int mt = 0; mt < 4; ++mt)
#pragma unroll
                for (int nt = 0; nt < 4; ++nt)
                    acc[mt][nt] = __builtin_amdgcn_mfma_f32_16x16x32_bf16(a[mt], b[nt], acc[mt][nt], 0, 0, 0);
        }

        // epilogue: p = relu(acc) . W4 over this wave's 64 cols
        float p[4][4];
#pragma unroll
        for (int mt = 0; mt < 4; ++mt)
#pragma unroll
            for (int r = 0; r < 4; ++r) {
                float s = 0.0f;
#pragma unroll
                for (int nt = 0; nt < 4; ++nt)
                    s += fmaxf(acc[mt][nt][r], 0.0f) * w4v[nt];
                p[mt][r] = s;
            }
#pragma unroll
        for (int off = 1; off < 16; off <<= 1)
#pragma unroll
            for (int mt = 0; mt < 4; ++mt)
#pragma unroll
                for (int r = 0; r < 4; ++r)
                    p[mt][r] += __shfl_xor(p[mt][r], off, 64);

        // stage next tile's A while results drain
        if (tt + 1 < TPB) WRITE_A(buf ^ 1);
        if (cl == 0) {
#pragma unroll
            for (int mt = 0; mt < 4; ++mt)
#pragma unroll
                for (int r = 0; r < 4; ++r)
                    partial[buf][w][mt * 16 + q * 4 + r] = p[mt][r];
        }
        __syncthreads();
        if (tt + 2 < TPB) ISSUE_GATHER(base + tt + 2);   // overlaps next MFMA phase
        if (t < 64) {
            float logit = partial[buf][0][t] + partial[buf][1][t] +
                          partial[buf][2][t] + partial[buf][3][t] + b4v;
            out[(base + tt) * 64 + t] = 1.0f / (1.0f + __expf(-logit));
        }
    }
#undef ISSUE_GATHER
#undef WRITE_A
}

extern "C" void kernel_launch(void* const* d_in, const int* in_sizes, int n_in,
                              void* d_out, int out_size, void* d_ws, size_t ws_size,
                              hipStream_t stream) {
    const float* x  = (const float*)d_in[0];
    const void*  ei = d_in[1];
    const float* W1 = (const float*)d_in[2];
    const float* b1 = (const float*)d_in[3];
    const float* W2 = (const float*)d_in[4];
    const float* b2 = (const float*)d_in[5];
    const float* W3 = (const float*)d_in[6];
    const float* b3 = (const float*)d_in[7];
    const float* W4 = (const float*)d_in[8];
    const float* b4 = (const float*)d_in[9];

    char* ws = (char*)d_ws;
    int* flag            = (int*)ws;
    unsigned short* w1s  = (unsigned short*)(ws + 256);
    unsigned short* w2s  = (unsigned short*)(ws + 256 + 65536);
    unsigned short* w3s  = (unsigned short*)(ws + 256 + 131072);
    unsigned short* hbf  = (unsigned short*)(ws + 256 + 262144);

    prep_kernel<<<512, 256, 0, stream>>>(W1, W2, W3, ei, w1s, w2s, w3s, flag);
    node_enc<<<(NN + 63) / 64, 256, 0, stream>>>(x, b1, b2, w1s, w2s, hbf);
    edge_mlp<<<NT / TPB, 256, 0, stream>>>(ei, hbf, w3s, b3, W4, b4, flag, (float*)d_out);
}

// Round 3
// 482.821 us; speedup vs baseline: 1.2546x; 1.2546x over previous
//
#include <hip/hip_runtime.h>

// PPAModel: node encoder (2-layer MLP) -> edge gather/concat -> edge MLP -> sigmoid
// IN=128, HID=256, OUT=128, N_NODES=100000, N_EDGES=1000000
//
// ws layout:
//   [0,256)            : int flag (1 => edge_index stored as int64)
//   [256, +64KB)       : W1 bf16 swizzled  [k/8][n][k%8], K=128,N=256
//   [65792, +64KB)     : W2 bf16 swizzled  K=256,N=128
//   [131328, +128KB)   : W3 bf16 swizzled  K=256,N=256
//   [262400, +25.6MB)  : h table bf16 [100000][128]
//
// edge_mlp v3: double-buffered LDS A-tile filled by global_load_lds GATHER DMA
// (per-lane global addr, zero data registers -> no spill), XOR-swizzled rows
// (row stride 512B gapless, required by the DMA's lane*16 LDS mapping;
// swizzle keeps ds_read_b128 conflict-free).

#define NN 100000
#define NE 1000000
#define NT 15625     // NE/64 edge tiles
#define TPB 5        // tiles per block (3125 * 5 == 15625, exact)

typedef __attribute__((ext_vector_type(8))) __bf16 bf16x8;
typedef __attribute__((ext_vector_type(4))) float f32x4;
typedef __attribute__((ext_vector_type(4))) unsigned short us4;

__device__ __forceinline__ unsigned short f2bf(float f) {
    unsigned u = __float_as_uint(f);
    return (unsigned short)((u + 0x7FFFu + ((u >> 16) & 1u)) >> 16);
}

#define GLD16(g, l)                                                         \
    __builtin_amdgcn_global_load_lds(                                       \
        (__attribute__((address_space(1))) void*)(g),                       \
        (__attribute__((address_space(3))) void*)(l), 16, 0, 0)

// ---------------- prep: swizzle weights to bf16, detect index dtype -------
__global__ void prep_kernel(const float* __restrict__ W1,
                            const float* __restrict__ W2,
                            const float* __restrict__ W3,
                            const void* __restrict__ eidx,
                            unsigned short* __restrict__ w1s,
                            unsigned short* __restrict__ w2s,
                            unsigned short* __restrict__ w3s,
                            int* __restrict__ flag) {
    int t = blockIdx.x * blockDim.x + threadIdx.x;
    if (t < 32768) {                       // W1: K=128, N=256
        int k = t >> 8, n = t & 255;
        w1s[(k >> 3) * 2048 + n * 8 + (k & 7)] = f2bf(W1[t]);
    } else if (t < 65536) {                // W2: K=256, N=128
        int i = t - 32768;
        int k = i >> 7, n = i & 127;
        w2s[(k >> 3) * 1024 + n * 8 + (k & 7)] = f2bf(W2[i]);
    } else if (t < 131072) {               // W3: K=256, N=256
        int i = t - 65536;
        int k = i >> 8, n = i & 255;
        w3s[(k >> 3) * 2048 + n * 8 + (k & 7)] = f2bf(W3[i]);
    }
    if (t == 0) {
        const unsigned* u = (const unsigned*)eidx;
        int all0 = 1;
        for (int i = 0; i < 32; ++i) all0 &= (u[2 * i + 1] == 0u);
        *flag = all0;
    }
}

// ---------------- phase 1: fused node encoder (unchanged from r2) ---------
__global__ __launch_bounds__(256, 2) void node_enc(
    const float* __restrict__ x, const float* __restrict__ b1,
    const float* __restrict__ b2, const unsigned short* __restrict__ w1s,
    const unsigned short* __restrict__ w2s, unsigned short* __restrict__ hbf) {
    __shared__ __align__(16) unsigned short A1[64 * 136];  // 17408 B
    __shared__ __align__(16) unsigned short A2[64 * 264];  // 33792 B

    const int t = threadIdx.x, lane = t & 63, w = t >> 6;
    const int cl = lane & 15, q = lane >> 4;
    const int m0 = blockIdx.x * 64;

    {
        const float4* x4 = (const float4*)x;
#pragma unroll
        for (int i = 0; i < 8; ++i) {
            int lin = i * 256 + t;
            int m = lin >> 5, c = lin & 31;
            int node = m0 + m;
            if (node > NN - 1) node = NN - 1;
            float4 v = x4[node * 32 + c];
            us4 b;
            b.x = f2bf(v.x); b.y = f2bf(v.y); b.z = f2bf(v.z); b.w = f2bf(v.w);
            *(us4*)(A1 + m * 136 + c * 4) = b;
        }
    }
    __syncthreads();

    const int nb = w * 64;
    float b1v[4];
#pragma unroll
    for (int nt = 0; nt < 4; ++nt) b1v[nt] = b1[nb + nt * 16 + cl];
    f32x4 acc[4][4];
#pragma unroll
    for (int mt = 0; mt < 4; ++mt)
#pragma unroll
        for (int nt = 0; nt < 4; ++nt)
            acc[mt][nt] = (f32x4){b1v[nt], b1v[nt], b1v[nt], b1v[nt]};
#pragma unroll
    for (int s = 0; s < 4; ++s) {   // K=128
        bf16x8 a[4], b[4];
#pragma unroll
        for (int mt = 0; mt < 4; ++mt)
            a[mt] = *(const bf16x8*)(A1 + (mt * 16 + cl) * 136 + s * 32 + q * 8);
#pragma unroll
        for (int nt = 0; nt < 4; ++nt)
            b[nt] = *(const bf16x8*)(w1s + (s * 4 + q) * 2048 + (nb + nt * 16 + cl) * 8);
#pragma unroll
        for (int mt = 0; mt < 4; ++mt)
#pragma unroll
            for (int nt = 0; nt < 4; ++nt)
                acc[mt][nt] = __builtin_amdgcn_mfma_f32_16x16x32_bf16(a[mt], b[nt], acc[mt][nt], 0, 0, 0);
    }

#pragma unroll
    for (int mt = 0; mt < 4; ++mt)
#pragma unroll
        for (int nt = 0; nt < 4; ++nt)
#pragma unroll
            for (int r = 0; r < 4; ++r) {
                float v = fmaxf(acc[mt][nt][r], 0.0f);
                A2[(mt * 16 + q * 4 + r) * 264 + nb + nt * 16 + cl] = f2bf(v);
            }
    __syncthreads();

    const int nb2 = w * 32;
    float b2v[2];
#pragma unroll
    for (int nt = 0; nt < 2; ++nt) b2v[nt] = b2[nb2 + nt * 16 + cl];
    f32x4 acc2[4][2];
#pragma unroll
    for (int mt = 0; mt < 4; ++mt)
#pragma unroll
        for (int nt = 0; nt < 2; ++nt)
            acc2[mt][nt] = (f32x4){b2v[nt], b2v[nt], b2v[nt], b2v[nt]};
#pragma unroll
    for (int s = 0; s < 8; ++s) {   // K=256
        bf16x8 a[4], b[2];
#pragma unroll
        for (int mt = 0; mt < 4; ++mt)
            a[mt] = *(const bf16x8*)(A2 + (mt * 16 + cl) * 264 + s * 32 + q * 8);
#pragma unroll
        for (int nt = 0; nt < 2; ++nt)
            b[nt] = *(const bf16x8*)(w2s + (s * 4 + q) * 1024 + (nb2 + nt * 16 + cl) * 8);
#pragma unroll
        for (int mt = 0; mt < 4; ++mt)
#pragma unroll
            for (int nt = 0; nt < 2; ++nt)
                acc2[mt][nt] = __builtin_amdgcn_mfma_f32_16x16x32_bf16(a[mt], b[nt], acc2[mt][nt], 0, 0, 0);
    }
#pragma unroll
    for (int mt = 0; mt < 4; ++mt)
#pragma unroll
        for (int nt = 0; nt < 2; ++nt)
#pragma unroll
            for (int r = 0; r < 4; ++r) {
                int node = m0 + mt * 16 + q * 4 + r;
                if (node < NN)
                    hbf[node * 128 + nb2 + nt * 16 + cl] = f2bf(acc2[mt][nt][r]);
            }
}

// ---------------- phase 2: edge MLP, DMA-gather double-buffer pipeline ----
__global__ __launch_bounds__(256, 2) void edge_mlp(
    const void* __restrict__ eidx, const unsigned short* __restrict__ hbf,
    const unsigned short* __restrict__ w3s, const float* __restrict__ b3,
    const float* __restrict__ W4, const float* __restrict__ b4,
    const int* __restrict__ flag, float* __restrict__ out) {
    // A: [buf][64 rows][256 k] bf16, row stride 512 B (gapless for DMA),
    // XOR swizzle: 16B-chunk pc = c ^ (row & 15). 2 x 32 KB.
    __shared__ __align__(16) unsigned short A[2][16384];
    __shared__ float partial[2][4][64];

    const int t = threadIdx.x, lane = t & 63, w = t >> 6;
    const int cl = lane & 15, q = lane >> 4;
    const int base = blockIdx.x * TPB;
    const bool i64f = (*flag != 0);
    const int* ei32 = (const int*)eidx;
    const long long* ei64 = (const long long*)eidx;

    // epilogue constants (this wave's 64 N-cols)
    const int nb = w * 64;
    float b3v[4], w4v[4];
#pragma unroll
    for (int nt = 0; nt < 4; ++nt) {
        int n = nb + nt * 16 + cl;
        b3v[nt] = b3[n];
        w4v[nt] = W4[n];
    }
    const float b4v = b4[0];

    // staging geometry: wave w owns rows w*16..w*16+15. Per DMA instr i
    // (0..7): LDS = A[buf] + w*8192 + i*1024 bytes, lane l -> +l*16.
    // lane l covers local row ml = 2*i + (l>>5), physical chunk pc = l&31,
    // logical chunk c = pc ^ ml (bit4 preserved: half = pc>>4).
    const int pc = lane & 31;
    const int rhi = lane >> 5;
    const int half = pc >> 4;

    int nodes[8];
#define LOAD_IDX(tile)                                                       \
    _Pragma("unroll") for (int i = 0; i < 8; ++i) {                          \
        int ml = 2 * i + rhi;                                                \
        int e = (tile) * 64 + w * 16 + ml;                                   \
        int eo = half ? (NE + e) : e;                                        \
        int nd = i64f ? (int)ei64[eo] : ei32[eo];                            \
        nd = nd < 0 ? 0 : (nd > NN - 1 ? NN - 1 : nd);                       \
        nodes[i] = nd;                                                       \
    }
#define ISSUE_GLD(buf)                                                       \
    _Pragma("unroll") for (int i = 0; i < 8; ++i) {                          \
        int ml = 2 * i + rhi;                                                \
        int kc = (pc ^ ml) & 15;                                             \
        const unsigned short* gp = hbf + (long)nodes[i] * 128 + kc * 8;      \
        char* lp = (char*)&A[buf][0] + w * 8192 + i * 1024;                  \
        GLD16(gp, lp);                                                       \
    }
#define MSTEP(s)                                                             \
    {                                                                        \
        bf16x8 a[4], b[4];                                                   \
        _Pragma("unroll") for (int mt = 0; mt < 4; ++mt)                     \
            a[mt] = *(const bf16x8*)(Ab + (mt * 16 + cl) * 256 +             \
                                     (((s) * 4 + q) ^ cl) * 8);              \
        _Pragma("unroll") for (int nt = 0; nt < 4; ++nt)                     \
            b[nt] = *(const bf16x8*)(w3s + ((s) * 4 + q) * 2048 +            \
                                     (nb + nt * 16 + cl) * 8);               \
        _Pragma("unroll") for (int mt = 0; mt < 4; ++mt)                     \
            _Pragma("unroll") for (int nt = 0; nt < 4; ++nt)                 \
                acc[mt][nt] = __builtin_amdgcn_mfma_f32_16x16x32_bf16(       \
                    a[mt], b[nt], acc[mt][nt], 0, 0, 0);                     \
    }

    // prologue: stage tile 0 into buf 0 (drained by first barrier)
    LOAD_IDX(base);
    ISSUE_GLD(0);
    __syncthreads();

    for (int tt = 0; tt < TPB; ++tt) {
        const int buf = tt & 1;
        const unsigned short* Ab = &A[buf][0];

        f32x4 acc[4][4];
#pragma unroll
        for (int mt = 0; mt < 4; ++mt)
#pragma unroll
            for (int nt = 0; nt < 4; ++nt)
                acc[mt][nt] = (f32x4){b3v[nt], b3v[nt], b3v[nt], b3v[nt]};

        if (tt + 1 < TPB) LOAD_IDX(base + tt + 1);
        MSTEP(0) MSTEP(1) MSTEP(2)
        if (tt + 1 < TPB) {
            const int nbuf = buf ^ 1;   // read by tt-1, safe after barrier
            ISSUE_GLD(nbuf);
        }
        MSTEP(3) MSTEP(4) MSTEP(5) MSTEP(6) MSTEP(7)

        // epilogue: p = relu(acc) . W4 over this wave's 64 cols
        float p[4][4];
#pragma unroll
        for (int mt = 0; mt < 4; ++mt)
#pragma unroll
            for (int r = 0; r < 4; ++r) {
                float s = 0.0f;
#pragma unroll
                for (int nt = 0; nt < 4; ++nt)
                    s += fmaxf(acc[mt][nt][r], 0.0f) * w4v[nt];
                p[mt][r] = s;
            }
#pragma unroll
        for (int off = 1; off < 16; off <<= 1)
#pragma unroll
            for (int mt = 0; mt < 4; ++mt)
#pragma unroll
                for (int r = 0; r < 4; ++r)
                    p[mt][r] += __shfl_xor(p[mt][r], off, 64);
        if (cl == 0) {
#pragma unroll
            for (int mt = 0; mt < 4; ++mt)
#pragma unroll
                for (int r = 0; r < 4; ++r)
                    partial[buf][w][mt * 16 + q * 4 + r] = p[mt][r];
        }
        __syncthreads();   // drains next tile's DMA (issued ~5 MSTEPs ago)
        if (t < 64) {
            float logit = partial[buf][0][t] + partial[buf][1][t] +
                          partial[buf][2][t] + partial[buf][3][t] + b4v;
            out[(base + tt) * 64 + t] = 1.0f / (1.0f + __expf(-logit));
        }
    }
#undef LOAD_IDX
#undef ISSUE_GLD
#undef MSTEP
}

extern "C" void kernel_launch(void* const* d_in, const int* in_sizes, int n_in,
                              void* d_out, int out_size, void* d_ws, size_t ws_size,
                              hipStream_t stream) {
    const float* x  = (const float*)d_in[0];
    const void*  ei = d_in[1];
    const float* W1 = (const float*)d_in[2];
    const float* b1 = (const float*)d_in[3];
    const float* W2 = (const float*)d_in[4];
    const float* b2 = (const float*)d_in[5];
    const float* W3 = (const float*)d_in[6];
    const float* b3 = (const float*)d_in[7];
    const float* W4 = (const float*)d_in[8];
    const float* b4 = (const float*)d_in[9];

    char* ws = (char*)d_ws;
    int* flag            = (int*)ws;
    unsigned short* w1s  = (unsigned short*)(ws + 256);
    unsigned short* w2s  = (unsigned short*)(ws + 256 + 65536);
    unsigned short* w3s  = (unsigned short*)(ws + 256 + 131072);
    unsigned short* hbf  = (unsigned short*)(ws + 256 + 262144);

    prep_kernel<<<512, 256, 0, stream>>>(W1, W2, W3, ei, w1s, w2s, w3s, flag);
    node_enc<<<(NN + 63) / 64, 256, 0, stream>>>(x, b1, b2, w1s, w2s, hbf);
    edge_mlp<<<NT / TPB, 256, 0, stream>>>(ei, hbf, w3s, b3, W4, b4, flag, (float*)d_out);
}

// Round 4
// 367.427 us; speedup vs baseline: 1.6486x; 1.3141x over previous
//
#include <hip/hip_runtime.h>

// PPAModel: node encoder (2-layer MLP) -> edge gather/concat -> edge MLP -> sigmoid
// IN=128, HID=256, OUT=128, N_NODES=100000, N_EDGES=1000000
//
// ws layout:
//   [0,256)            : int flag (1 => edge_index stored as int64)
//   [256, +64KB)       : W1 bf16 swizzled  [k/8][n][k%8], K=128,N=256
//   [65792, +64KB)     : W2 bf16 swizzled  K=256,N=128
//   [131328, +128KB)   : W3 bf16 swizzled  K=256,N=256
//   [262400, +25.6MB)  : h table bf16 [100000][128]
//
// edge_mlp v4: r1 skeleton (clean regs) + W3 held ENTIRELY in registers per
// wave (8 waves x 32 cols, w3r[8][2] = 64 VGPRs, loaded once per block) ->
// zero global loads in the K-loop. Persistent blocks (grid 512, strided
// tiles), double-buffered XOR-swizzled A-tile (r3 layout, 0 bank conflicts),
// gather via plain loads with short-lived registers.

#define NN 100000
#define NE 1000000
#define NT 15625     // NE/64 edge tiles
#define GRID_E 512

typedef __attribute__((ext_vector_type(8))) __bf16 bf16x8;
typedef __attribute__((ext_vector_type(4))) float f32x4;
typedef __attribute__((ext_vector_type(4))) unsigned short us4;

__device__ __forceinline__ unsigned short f2bf(float f) {
    unsigned u = __float_as_uint(f);
    return (unsigned short)((u + 0x7FFFu + ((u >> 16) & 1u)) >> 16);
}

// ---------------- prep: swizzle weights to bf16, detect index dtype -------
__global__ void prep_kernel(const float* __restrict__ W1,
                            const float* __restrict__ W2,
                            const float* __restrict__ W3,
                            const void* __restrict__ eidx,
                            unsigned short* __restrict__ w1s,
                            unsigned short* __restrict__ w2s,
                            unsigned short* __restrict__ w3s,
                            int* __restrict__ flag) {
    int t = blockIdx.x * blockDim.x + threadIdx.x;
    if (t < 32768) {                       // W1: K=128, N=256
        int k = t >> 8, n = t & 255;
        w1s[(k >> 3) * 2048 + n * 8 + (k & 7)] = f2bf(W1[t]);
    } else if (t < 65536) {                // W2: K=256, N=128
        int i = t - 32768;
        int k = i >> 7, n = i & 127;
        w2s[(k >> 3) * 1024 + n * 8 + (k & 7)] = f2bf(W2[i]);
    } else if (t < 131072) {               // W3: K=256, N=256
        int i = t - 65536;
        int k = i >> 8, n = i & 255;
        w3s[(k >> 3) * 2048 + n * 8 + (k & 7)] = f2bf(W3[i]);
    }
    if (t == 0) {
        const unsigned* u = (const unsigned*)eidx;
        int all0 = 1;
        for (int i = 0; i < 32; ++i) all0 &= (u[2 * i + 1] == 0u);
        *flag = all0;
    }
}

// ---------------- phase 1: fused node encoder, weights in registers -------
__global__ __launch_bounds__(256, 2) void node_enc(
    const float* __restrict__ x, const float* __restrict__ b1,
    const float* __restrict__ b2, const unsigned short* __restrict__ w1s,
    const unsigned short* __restrict__ w2s, unsigned short* __restrict__ hbf) {
    __shared__ __align__(16) unsigned short A1[64 * 136];  // 17408 B
    __shared__ __align__(16) unsigned short A2[64 * 264];  // 33792 B

    const int t = threadIdx.x, lane = t & 63, w = t >> 6;
    const int cl = lane & 15, q = lane >> 4;
    const int m0 = blockIdx.x * 64;

    // stage x rows -> bf16 LDS
    {
        const float4* x4 = (const float4*)x;
#pragma unroll
        for (int i = 0; i < 8; ++i) {
            int lin = i * 256 + t;
            int m = lin >> 5, c = lin & 31;
            int node = m0 + m;
            if (node > NN - 1) node = NN - 1;
            float4 v = x4[node * 32 + c];
            us4 b;
            b.x = f2bf(v.x); b.y = f2bf(v.y); b.z = f2bf(v.z); b.w = f2bf(v.w);
            *(us4*)(A1 + m * 136 + c * 4) = b;
        }
    }

    // preload W1 slice into regs (wave owns 64 N-cols)
    const int nb = w * 64;
    bf16x8 w1r[4][4];
#pragma unroll
    for (int s = 0; s < 4; ++s)
#pragma unroll
        for (int nt = 0; nt < 4; ++nt)
            w1r[s][nt] = *(const bf16x8*)(w1s + (s * 4 + q) * 2048 +
                                          (nb + nt * 16 + cl) * 8);
    float b1v[4];
#pragma unroll
    for (int nt = 0; nt < 4; ++nt) b1v[nt] = b1[nb + nt * 16 + cl];
    __syncthreads();

    // GEMM1: [64x128]x[128x256]
    f32x4 acc[4][4];
#pragma unroll
    for (int mt = 0; mt < 4; ++mt)
#pragma unroll
        for (int nt = 0; nt < 4; ++nt)
            acc[mt][nt] = (f32x4){b1v[nt], b1v[nt], b1v[nt], b1v[nt]};
#pragma unroll
    for (int s = 0; s < 4; ++s) {
        bf16x8 a[4];
#pragma unroll
        for (int mt = 0; mt < 4; ++mt)
            a[mt] = *(const bf16x8*)(A1 + (mt * 16 + cl) * 136 + s * 32 + q * 8);
#pragma unroll
        for (int mt = 0; mt < 4; ++mt)
#pragma unroll
            for (int nt = 0; nt < 4; ++nt)
                acc[mt][nt] = __builtin_amdgcn_mfma_f32_16x16x32_bf16(a[mt], w1r[s][nt], acc[mt][nt], 0, 0, 0);
    }

    // relu -> A2 [m][k] bf16
#pragma unroll
    for (int mt = 0; mt < 4; ++mt)
#pragma unroll
        for (int nt = 0; nt < 4; ++nt)
#pragma unroll
            for (int r = 0; r < 4; ++r) {
                float v = fmaxf(acc[mt][nt][r], 0.0f);
                A2[(mt * 16 + q * 4 + r) * 264 + nb + nt * 16 + cl] = f2bf(v);
            }

    // preload W2 slice (wave owns 32 N-cols); w1r/acc dead now
    const int nb2 = w * 32;
    bf16x8 w2r[8][2];
#pragma unroll
    for (int s = 0; s < 8; ++s)
#pragma unroll
        for (int nt = 0; nt < 2; ++nt)
            w2r[s][nt] = *(const bf16x8*)(w2s + (s * 4 + q) * 1024 +
                                          (nb2 + nt * 16 + cl) * 8);
    float b2v[2];
#pragma unroll
    for (int nt = 0; nt < 2; ++nt) b2v[nt] = b2[nb2 + nt * 16 + cl];
    __syncthreads();

    // GEMM2: [64x256]x[256x128]
    f32x4 acc2[4][2];
#pragma unroll
    for (int mt = 0; mt < 4; ++mt)
#pragma unroll
        for (int nt = 0; nt < 2; ++nt)
            acc2[mt][nt] = (f32x4){b2v[nt], b2v[nt], b2v[nt], b2v[nt]};
#pragma unroll
    for (int s = 0; s < 8; ++s) {
        bf16x8 a[4];
#pragma unroll
        for (int mt = 0; mt < 4; ++mt)
            a[mt] = *(const bf16x8*)(A2 + (mt * 16 + cl) * 264 + s * 32 + q * 8);
#pragma unroll
        for (int mt = 0; mt < 4; ++mt)
#pragma unroll
            for (int nt = 0; nt < 2; ++nt)
                acc2[mt][nt] = __builtin_amdgcn_mfma_f32_16x16x32_bf16(a[mt], w2r[s][nt], acc2[mt][nt], 0, 0, 0);
    }
#pragma unroll
    for (int mt = 0; mt < 4; ++mt)
#pragma unroll
        for (int nt = 0; nt < 2; ++nt)
#pragma unroll
            for (int r = 0; r < 4; ++r) {
                int node = m0 + mt * 16 + q * 4 + r;
                if (node < NN)
                    hbf[node * 128 + nb2 + nt * 16 + cl] = f2bf(acc2[mt][nt][r]);
            }
}

// ---------------- phase 2: edge MLP, W3 in registers, persistent blocks ---
__global__ __launch_bounds__(512, 2) void edge_mlp(
    const void* __restrict__ eidx, const unsigned short* __restrict__ hbf,
    const unsigned short* __restrict__ w3s, const float* __restrict__ b3,
    const float* __restrict__ W4, const float* __restrict__ b4,
    const int* __restrict__ flag, float* __restrict__ out) {
    // A: [buf][64 rows][256 k] bf16, row stride 512 B, XOR-swizzled 16B
    // chunks: phys = logical ^ (row & 15)  (bit4 = src/dst half preserved
    // because logical-chunk bit4 xor'd with <=15 keeps bit4). 2 x 32 KB.
    __shared__ __align__(16) unsigned short A[2][16384];
    __shared__ float partial[2][8][64];

    const int t = threadIdx.x, lane = t & 63, w = t >> 6;  // w: 0..7
    const int cl = lane & 15, q = lane >> 4;
    const bool i64f = (*flag != 0);
    const int* ei32 = (const int*)eidx;
    const long long* ei64 = (const long long*)eidx;

    // epilogue constants + full W3 slice in registers (wave owns 32 N-cols)
    const int nb = w * 32;
    float b3v[2], w4v[2];
#pragma unroll
    for (int nt = 0; nt < 2; ++nt) {
        int n = nb + nt * 16 + cl;
        b3v[nt] = b3[n];
        w4v[nt] = W4[n];
    }
    const float b4v = b4[0];
    bf16x8 w3r[8][2];
#pragma unroll
    for (int s = 0; s < 8; ++s)
#pragma unroll
        for (int nt = 0; nt < 2; ++nt)
            w3r[s][nt] = *(const bf16x8*)(w3s + (s * 4 + q) * 2048 +
                                          (nb + nt * 16 + cl) * 8);

    // gather geometry: thread covers rows m0+16i (i=0..3), chunk c (16B).
    const int c = t & 31, m0 = t >> 5;        // m0: 0..15 == (row & 15)
    const int half = c >> 4, kc = c & 15;
    const int pc = c ^ m0;                     // physical chunk (bit4 kept)

    int nds[4];
    uint4 gv[4];
#define LOAD_IDX(tile)                                                       \
    _Pragma("unroll") for (int i = 0; i < 4; ++i) {                          \
        int e = (tile) * 64 + m0 + 16 * i;                                   \
        int eo = half ? (NE + e) : e;                                        \
        int nd = i64f ? (int)ei64[eo] : ei32[eo];                            \
        nds[i] = nd < 0 ? 0 : (nd > NN - 1 ? NN - 1 : nd);                   \
    }
#define GATHER()                                                             \
    _Pragma("unroll") for (int i = 0; i < 4; ++i)                            \
        gv[i] = *(const uint4*)(hbf + (long)nds[i] * 128 + kc * 8);
#define WRITE_A(buf)                                                         \
    _Pragma("unroll") for (int i = 0; i < 4; ++i)                            \
        *(uint4*)(&A[buf][(m0 + 16 * i) * 256 + pc * 8]) = gv[i];
#define MSTEP(s)                                                             \
    {                                                                        \
        bf16x8 a[4];                                                         \
        _Pragma("unroll") for (int mt = 0; mt < 4; ++mt)                     \
            a[mt] = *(const bf16x8*)(Ab + (mt * 16 + cl) * 256 +             \
                                     (((s) * 4 + q) ^ cl) * 8);              \
        _Pragma("unroll") for (int mt = 0; mt < 4; ++mt)                     \
            _Pragma("unroll") for (int nt = 0; nt < 2; ++nt)                 \
                acc[mt][nt] = __builtin_amdgcn_mfma_f32_16x16x32_bf16(       \
                    a[mt], w3r[s][nt], acc[mt][nt], 0, 0, 0);                \
    }

    // prologue: stage first tile
    int tile = blockIdx.x;
    LOAD_IDX(tile);
    GATHER();
    WRITE_A(0);
    __syncthreads();

    int buf = 0;
    for (;;) {
        const int next = tile + GRID_E;
        const bool has_next = next < NT;
        const unsigned short* Ab = &A[buf][0];

        f32x4 acc[4][2];
#pragma unroll
        for (int mt = 0; mt < 4; ++mt)
#pragma unroll
            for (int nt = 0; nt < 2; ++nt)
                acc[mt][nt] = (f32x4){b3v[nt], b3v[nt], b3v[nt], b3v[nt]};

        // issue next tile's gather early; data lands while MFMAs run
        if (has_next) {
            LOAD_IDX(next);
            GATHER();
        }
        MSTEP(0) MSTEP(1) MSTEP(2) MSTEP(3)
        MSTEP(4) MSTEP(5) MSTEP(6) MSTEP(7)
        if (has_next) WRITE_A(buf ^ 1);   // buf^1 free since last barrier

        // epilogue: p = relu(acc) . W4 over this wave's 32 cols
        float p[4][4];
#pragma unroll
        for (int mt = 0; mt < 4; ++mt)
#pragma unroll
            for (int r = 0; r < 4; ++r) {
                float s = 0.0f;
#pragma unroll
                for (int nt = 0; nt < 2; ++nt)
                    s += fmaxf(acc[mt][nt][r], 0.0f) * w4v[nt];
                p[mt][r] = s;
            }
#pragma unroll
        for (int off = 1; off < 16; off <<= 1)
#pragma unroll
            for (int mt = 0; mt < 4; ++mt)
#pragma unroll
                for (int r = 0; r < 4; ++r)
                    p[mt][r] += __shfl_xor(p[mt][r], off, 64);
        if (cl == 0) {
#pragma unroll
            for (int mt = 0; mt < 4; ++mt)
#pragma unroll
                for (int r = 0; r < 4; ++r)
                    partial[buf][w][mt * 16 + q * 4 + r] = p[mt][r];
        }
        __syncthreads();
        if (t < 64) {
            float logit = b4v;
#pragma unroll
            for (int j = 0; j < 8; ++j) logit += partial[buf][j][t];
            out[tile * 64 + t] = 1.0f / (1.0f + __expf(-logit));
        }
        if (!has_next) break;
        tile = next;
        buf ^= 1;
    }
#undef LOAD_IDX
#undef GATHER
#undef WRITE_A
#undef MSTEP
}

extern "C" void kernel_launch(void* const* d_in, const int* in_sizes, int n_in,
                              void* d_out, int out_size, void* d_ws, size_t ws_size,
                              hipStream_t stream) {
    const float* x  = (const float*)d_in[0];
    const void*  ei = d_in[1];
    const float* W1 = (const float*)d_in[2];
    const float* b1 = (const float*)d_in[3];
    const float* W2 = (const float*)d_in[4];
    const float* b2 = (const float*)d_in[5];
    const float* W3 = (const float*)d_in[6];
    const float* b3 = (const float*)d_in[7];
    const float* W4 = (const float*)d_in[8];
    const float* b4 = (const float*)d_in[9];

    char* ws = (char*)d_ws;
    int* flag            = (int*)ws;
    unsigned short* w1s  = (unsigned short*)(ws + 256);
    unsigned short* w2s  = (unsigned short*)(ws + 256 + 65536);
    unsigned short* w3s  = (unsigned short*)(ws + 256 + 131072);
    unsigned short* hbf  = (unsigned short*)(ws + 256 + 262144);

    prep_kernel<<<512, 256, 0, stream>>>(W1, W2, W3, ei, w1s, w2s, w3s, flag);
    node_enc<<<(NN + 63) / 64, 256, 0, stream>>>(x, b1, b2, w1s, w2s, hbf);
    edge_mlp<<<GRID_E, 512, 0, stream>>>(ei, hbf, w3s, b3, W4, b4, flag, (float*)d_out);
}